// Round 1
// 344.885 us; speedup vs baseline: 1.0103x; 1.0103x over previous
//
#include <hip/hip_runtime.h>
#include <stdint.h>

// Problem constants (AdaBIGGAN last adaptive-conv stage), all tensors float32.
#define B_  32
#define C_  96
#define HW_ 16384   // 128*128
#define IN_ 148

typedef float f32x4 __attribute__((ext_vector_type(4)));

// ---------------------------------------------------------------------------
// Kernel 1: hypernetwork collapse (unchanged — a few µs, not the bottleneck).
//   scale[b,c] = y[b,:] . Wsum[c,:] + WbSum[c]
//   bias [b,c] = y[b,:] . Bg_w[c,:] + Bg_b[c]
// where Wsum[c,i] = sum_j Wg_w[(c*96+j)*148 + i], WbSum[c] = sum_j Wg_b[c*96+j].
// One block per c (96 blocks, 256 threads = 4 waves).
// ---------------------------------------------------------------------------
__global__ __launch_bounds__(256) void hyper_kernel(
    const float* __restrict__ Wg_w, const float* __restrict__ Wg_b,
    const float* __restrict__ Bg_w, const float* __restrict__ Bg_b,
    const float* __restrict__ y,
    float* __restrict__ scale, float* __restrict__ bias) {
    const int c   = blockIdx.x;
    const int tid = threadIdx.x;

    __shared__ float sW[IN_];   // column-sums of Wg_w rows for this c
    __shared__ float sB[IN_];   // Bg_w row for this c
    __shared__ float sWbS;      // sum of the Wg_b chunk

    if (tid < IN_) {
        float s = 0.f;
        const float* p = Wg_w + (size_t)c * C_ * IN_ + tid;
        #pragma unroll 4
        for (int j = 0; j < C_; ++j) s += p[(size_t)j * IN_];
        sW[tid] = s;
        sB[tid] = Bg_w[c * IN_ + tid];
    }
    if (tid < 64) {  // sum of 96 Wg_b entries, wave 0
        float v = Wg_b[c * C_ + tid];
        if (tid < C_ - 64) v += Wg_b[c * C_ + 64 + tid];
        #pragma unroll
        for (int off = 32; off > 0; off >>= 1) v += __shfl_down(v, off);
        if (tid == 0) sWbS = v;
    }
    __syncthreads();

    const int wave = tid >> 6, lane = tid & 63;
    for (int b = wave; b < B_; b += 4) {
        float y0 = y[b * IN_ + lane];
        float y1 = y[b * IN_ + 64 + lane];
        float ps = y0 * sW[lane] + y1 * sW[64 + lane];
        float pb = y0 * sB[lane] + y1 * sB[64 + lane];
        if (lane < IN_ - 128) {   // 148 = 64 + 64 + 20
            float y2 = y[b * IN_ + 128 + lane];
            ps += y2 * sW[128 + lane];
            pb += y2 * sB[128 + lane];
        }
        #pragma unroll
        for (int off = 32; off > 0; off >>= 1) {
            ps += __shfl_down(ps, off);
            pb += __shfl_down(pb, off);
        }
        if (lane == 0) {
            scale[b * C_ + c] = ps + sWbS;
            bias [b * C_ + c] = pb + Bg_b[c];
        }
    }
}

// ---------------------------------------------------------------------------
// Kernel 2: out = relu(h * scale[plane] + bias[plane]).
// One block per (b,c) plane: 3072 blocks (12/CU), 256 threads, 16 float4 each.
// Two batches of 8 independent nontemporal loads for MLP depth while staying
// near 64 VGPR (full occupancy). h/out are touched exactly once -> nt hints.
// ---------------------------------------------------------------------------
__global__ __launch_bounds__(256) void apply_kernel(
    const float* __restrict__ h, const float* __restrict__ scale,
    const float* __restrict__ bias, float* __restrict__ out) {
    const int plane = blockIdx.x;                       // b*C + c
    const float s  = scale[plane];
    const float bb = bias[plane];

    const f32x4* __restrict__ hp =
        reinterpret_cast<const f32x4*>(h) + (size_t)plane * (HW_ / 4) + threadIdx.x;
    f32x4* __restrict__ op =
        reinterpret_cast<f32x4*>(out) + (size_t)plane * (HW_ / 4) + threadIdx.x;

    #pragma unroll
    for (int half = 0; half < 2; ++half) {
        f32x4 v[8];
        #pragma unroll
        for (int i = 0; i < 8; ++i)
            v[i] = __builtin_nontemporal_load(hp + (half * 8 + i) * 256);
        #pragma unroll
        for (int i = 0; i < 8; ++i) {
            f32x4 o;
            o.x = fmaxf(fmaf(v[i].x, s, bb), 0.f);
            o.y = fmaxf(fmaf(v[i].y, s, bb), 0.f);
            o.z = fmaxf(fmaf(v[i].z, s, bb), 0.f);
            o.w = fmaxf(fmaf(v[i].w, s, bb), 0.f);
            __builtin_nontemporal_store(o, op + (half * 8 + i) * 256);
        }
    }
}

extern "C" void kernel_launch(void* const* d_in, const int* in_sizes, int n_in,
                              void* d_out, int out_size, void* d_ws, size_t ws_size,
                              hipStream_t stream) {
    const float* h    = (const float*)d_in[0];
    const float* y    = (const float*)d_in[1];
    const float* Wg_w = (const float*)d_in[2];
    const float* Wg_b = (const float*)d_in[3];
    const float* Bg_w = (const float*)d_in[4];
    const float* Bg_b = (const float*)d_in[5];
    float* out = (float*)d_out;

    // f32 scratch in d_ws: scale[B*C] then bias[B*C] (24 KB total).
    float* scale = (float*)d_ws;
    float* bias  = scale + B_ * C_;

    hyper_kernel<<<C_, 256, 0, stream>>>(Wg_w, Wg_b, Bg_w, Bg_b, y, scale, bias);

    apply_kernel<<<B_ * C_, 256, 0, stream>>>(h, scale, bias, out);
}

// Round 2
// 335.673 us; speedup vs baseline: 1.0380x; 1.0274x over previous
//
#include <hip/hip_runtime.h>
#include <stdint.h>

// Problem constants (AdaBIGGAN last adaptive-conv stage), all tensors float32.
#define B_  32
#define C_  96
#define HW_ 16384   // 128*128
#define IN_ 148

typedef float f32x4 __attribute__((ext_vector_type(4)));

// ---------------------------------------------------------------------------
// Fused kernel: one block per (b,c) plane. 3072 blocks, 256 threads.
//
//   scale[b,c] = y[b,:] . colsum(Wg_w[c*96:(c+1)*96, :]) + sum(Wg_b[c*96:...])
//   bias [b,c] = y[b,:] . Bg_w[c,:] + Bg_b[c]
//   out = relu(h * scale + bias)
//
// Schedule: issue 8 nontemporal h-loads per thread FIRST (HBM latency in
// flight), compute the per-block hyper dot while they fly (Wg_w chunk is
// L2-hot: 32 blocks share each channel; XCD swizzle keeps the per-XCD
// working set to 12 channels = 682 KB < 4 MiB L2), then apply + stream the
// second half. Removes the separate hyper kernel and its serialization.
// ---------------------------------------------------------------------------
__global__ __launch_bounds__(256) void fused_kernel(
    const float* __restrict__ h, const float* __restrict__ y,
    const float* __restrict__ Wg_w, const float* __restrict__ Wg_b,
    const float* __restrict__ Bg_w, const float* __restrict__ Bg_b,
    float* __restrict__ out) {
    // XCD-aware swizzle: consecutive blockIdx round-robin XCDs (blockIdx&7).
    // Give XCD x channels [x*12, (x+1)*12) so its L2 holds only 12 chunks.
    const int bid = blockIdx.x;           // [0, 3072)
    const int xcd = bid & 7;
    const int t   = bid >> 3;             // [0, 384)
    const int c   = xcd * 12 + (t % 12);  // [0, 96)
    const int b   = t / 12;               // [0, 32)
    const int tid = threadIdx.x;
    const int plane = b * C_ + c;

    const f32x4* __restrict__ hp =
        reinterpret_cast<const f32x4*>(h) + (size_t)plane * (HW_ / 4) + tid;
    f32x4* __restrict__ op =
        reinterpret_cast<f32x4*>(out) + (size_t)plane * (HW_ / 4) + tid;

    // --- (1) prefetch first half of h: 8 x float4 per thread, nontemporal ---
    f32x4 v[8];
    #pragma unroll
    for (int i = 0; i < 8; ++i)
        v[i] = __builtin_nontemporal_load(hp + i * 256);

    // --- (2) hyper: per-(b,c) scale/bias while h-loads are in flight ---
    float ps = 0.f, pb = 0.f;
    if (tid < IN_) {
        // column-sum of the 96x148 Wg_w chunk for channel c, column tid
        const float* p = Wg_w + (size_t)c * C_ * IN_ + tid;
        float a0 = 0.f, a1 = 0.f, a2 = 0.f, a3 = 0.f;
        #pragma unroll 6   // 24 loads in flight max alongside v[8]
        for (int j = 0; j < C_; j += 4) {
            a0 += p[(j + 0) * IN_];
            a1 += p[(j + 1) * IN_];
            a2 += p[(j + 2) * IN_];
            a3 += p[(j + 3) * IN_];
        }
        const float cs = (a0 + a1) + (a2 + a3);
        const float yv = y[b * IN_ + tid];
        ps = yv * cs;
        pb = yv * Bg_w[c * IN_ + tid];
    } else if (tid < IN_ + C_) {          // threads 148..243: Wg_b chunk sum
        ps = Wg_b[c * C_ + (tid - IN_)];
    } else if (tid == IN_ + C_) {         // thread 244: Bg_b
        pb = Bg_b[c];
    }
    // 64-lane butterfly reduce (inactive lanes contribute 0)
    #pragma unroll
    for (int off = 32; off > 0; off >>= 1) {
        ps += __shfl_xor(ps, off);
        pb += __shfl_xor(pb, off);
    }
    __shared__ float sPS[4], sPB[4];
    const int wave = tid >> 6, lane = tid & 63;
    if (lane == 0) { sPS[wave] = ps; sPB[wave] = pb; }
    __syncthreads();
    const float s  = (sPS[0] + sPS[1]) + (sPS[2] + sPS[3]);
    const float bb = (sPB[0] + sPB[1]) + (sPB[2] + sPB[3]);

    // --- (3) consume half 0 ---
    #pragma unroll
    for (int i = 0; i < 8; ++i) {
        f32x4 o;
        o.x = fmaxf(fmaf(v[i].x, s, bb), 0.f);
        o.y = fmaxf(fmaf(v[i].y, s, bb), 0.f);
        o.z = fmaxf(fmaf(v[i].z, s, bb), 0.f);
        o.w = fmaxf(fmaf(v[i].w, s, bb), 0.f);
        __builtin_nontemporal_store(o, op + i * 256);
    }
    // --- (4) stream half 1 ---
    #pragma unroll
    for (int i = 0; i < 8; ++i)
        v[i] = __builtin_nontemporal_load(hp + (8 + i) * 256);
    #pragma unroll
    for (int i = 0; i < 8; ++i) {
        f32x4 o;
        o.x = fmaxf(fmaf(v[i].x, s, bb), 0.f);
        o.y = fmaxf(fmaf(v[i].y, s, bb), 0.f);
        o.z = fmaxf(fmaf(v[i].z, s, bb), 0.f);
        o.w = fmaxf(fmaf(v[i].w, s, bb), 0.f);
        __builtin_nontemporal_store(o, op + (8 + i) * 256);
    }
}

extern "C" void kernel_launch(void* const* d_in, const int* in_sizes, int n_in,
                              void* d_out, int out_size, void* d_ws, size_t ws_size,
                              hipStream_t stream) {
    const float* h    = (const float*)d_in[0];
    const float* y    = (const float*)d_in[1];
    const float* Wg_w = (const float*)d_in[2];
    const float* Wg_b = (const float*)d_in[3];
    const float* Bg_w = (const float*)d_in[4];
    const float* Bg_b = (const float*)d_in[5];
    float* out = (float*)d_out;

    fused_kernel<<<B_ * C_, 256, 0, stream>>>(h, y, Wg_w, Wg_b, Bg_w, Bg_b, out);
}